// Round 12
// baseline (89.777 us; speedup 1.0000x reference)
//
#include <hip/hip_runtime.h>
#include <math.h>

#define HWSZ 36864            // 192*192
#define NTILE64 576           // 64-px tiles per image
#define NBLK 1152             // gemm blocks (2 images * 576)

typedef short bf16x8 __attribute__((ext_vector_type(8)));
typedef float f32x16 __attribute__((ext_vector_type(16)));
typedef unsigned int u32x4 __attribute__((ext_vector_type(4)));

__device__ __forceinline__ unsigned short f2bf(float x) {
    unsigned u = __float_as_uint(x);
    return (unsigned short)((u + 0x7fffu + ((u >> 16) & 1u)) >> 16);  // RNE
}

// barrier that does NOT drain vmcnt (T4)
__device__ __forceinline__ void block_sync_lds() {
    __builtin_amdgcn_sched_barrier(0);
    asm volatile("s_waitcnt lgkmcnt(0)" ::: "memory");
    __builtin_amdgcn_s_barrier();
    __builtin_amdgcn_sched_barrier(0);
}

// ---------------- precompute: A-fragments for all paths
// AfragW [s][r(4)][kt(4)][lane][e]: r<2 = D_s rows, r>=2 = MT_s rows
// AfragMS2 (fallback): MS2 = MSp - sum_s MT_s ; AfragSp (fast): MSp ; c1
__global__ void pre_all(const float* __restrict__ rw1, const float* __restrict__ rb1,
                        const float* __restrict__ aw, const float* __restrict__ ab,
                        const float* __restrict__ mu, const float* __restrict__ sg,
                        unsigned short* __restrict__ AfragW,
                        unsigned short* __restrict__ AfragMS2,
                        unsigned short* __restrict__ AfragSp, float* __restrict__ c1) {
    int i = blockIdx.x * 256 + threadIdx.x;
    if (i < 40960) {
        int s = i / 8192, rem = i % 8192;
        int r = rem / 2048, rem2 = rem % 2048;
        int t = rem2 / 512, q = rem2 % 512;
        int l = q >> 3, e = q & 7;
        int R = 32 * r + (l & 31);
        int k = 16 * t + 8 * (l >> 5) + e;
        float v;
        if (R < 64) {
            v = aw[s * 4096 + R * 64 + k] / sg[s * 64 + R];
        } else {
            int o = R - 64;
            const float* wp = rw1 + o * 960 + s * 192;
            const float* A  = aw + s * 4096 + k;
            const float* G  = sg + s * 64;
            float sum = 0.f;
            #pragma unroll 8
            for (int d = 0; d < 64; ++d)
                sum = fmaf(wp[64 + d] + wp[128 + d], A[d * 64] / G[d], sum);
            v = sum;
        }
        AfragW[i] = f2bf(v);
    } else if (i < 49152) {
        int j = (i - 40960) & 4095;
        bool isSp = (i >= 45056);
        int r = j / 2048, rem2 = j % 2048;
        int t = rem2 / 512, q = rem2 % 512;
        int l = q >> 3, e = q & 7;
        int o = 32 * r + (l & 31);
        int k = 16 * t + 8 * (l >> 5) + e;
        float sum = 0.f;
        for (int s = 0; s < 5; ++s) {
            const float* wp = rw1 + o * 960 + s * 192;
            const float* A  = aw + s * 4096 + k;
            const float* G  = sg + s * 64;
            if (isSp) {
                #pragma unroll 8
                for (int d = 0; d < 64; ++d)
                    sum = fmaf(wp[d] + wp[64 + d], A[d * 64] / G[d], sum);
            } else {
                #pragma unroll 8
                for (int d = 0; d < 64; ++d)
                    sum = fmaf(wp[d] - wp[128 + d], A[d * 64] / G[d], sum);
            }
        }
        if (isSp) AfragSp[j] = f2bf(sum); else AfragMS2[j] = f2bf(sum);
    } else if (i < 49216) {
        int o = i - 49152;
        float sum = rb1[o];
        for (int s = 0; s < 5; ++s) {
            const float* wp = rw1 + o * 960 + s * 192;
            #pragma unroll 8
            for (int d = 0; d < 64; ++d) {
                int sd = s * 64 + d;
                sum = fmaf(wp[d] + wp[64 + d], (ab[sd] - mu[sd]) / sg[sd], sum);
            }
        }
        c1[o] = sum;
    }
}

// ---------------- xpose: streaming transpose pass, both sides wave-linear.
// block = (b, s-plane, 256-px chunk): reads 64 rows x 1KB (T and S), computes
// X = T - S in fp32, LDS-transposes to MFMA fragment order, writes 4 x 8KB
// linear fragment tiles. s==0 blocks also emit S fragment tiles.
__global__ __launch_bounds__(256) void xpose(
        const float* __restrict__ S, const float* __restrict__ T,
        unsigned short* __restrict__ Xf, unsigned short* __restrict__ Sf) {
    __shared__ __align__(16) unsigned short tile[16384];   // 32 KB
    const int tid = threadIdx.x, w = tid >> 6, lane = tid & 63;
    const int bid = blockIdx.x;
    const int sidx = bid % 5;
    const int chunk = (bid / 5) % 144;
    const int b = bid / 720;
    const int px0 = chunk * 256;

    // wave w owns rows w*16 .. w*16+15  (=> kt = w fixed)
    const float* Sb = S + ((size_t)(b * 64) + w * 16) * HWSZ + px0 + lane * 4;
    const float* Tb = T + (((size_t)(b * 5) + sidx) * 64 + w * 16) * HWSZ + px0 + lane * 4;

    float4 sv[16], tv[16];
    #pragma unroll
    for (int k = 0; k < 16; ++k) sv[k] = *(const float4*)(Sb + (size_t)k * HWSZ);
    #pragma unroll
    for (int k = 0; k < 16; ++k) tv[k] = *(const float4*)(Tb + (size_t)k * HWSZ);

    auto stage = [&](bool isX) {
        #pragma unroll
        for (int k = 0; k < 16; ++k) {
            int hh = k >> 3, e = k & 7;
            #pragma unroll
            for (int pi = 0; pi < 4; ++pi) {
                int px = lane * 4 + pi;
                int tl = px >> 6, px64 = px & 63, ct = px64 >> 5, pxm = px64 & 31;
                float v = isX ? (((const float*)&tv[k])[pi] - ((const float*)&sv[k])[pi])
                              : ((const float*)&sv[k])[pi];
                tile[tl * 4096 + ((ct * 4 + w) * 64 + hh * 32 + pxm) * 8 + e] = f2bf(v);
            }
        }
    };
    auto writeout = [&](unsigned short* dstbase, size_t tstride_u16) {
        int tl = tid >> 6;
        const u32x4* src = (const u32x4*)&tile[tl * 4096];
        u32x4* dst = (u32x4*)(dstbase + (size_t)tl * tstride_u16);
        #pragma unroll
        for (int k2 = 0; k2 < 8; ++k2) dst[k2 * 64 + lane] = src[k2 * 64 + lane];
    };

    stage(true);
    block_sync_lds();
    {
        int t0 = chunk * 4;
        unsigned short* xb = Xf + (((size_t)(b * NTILE64 + t0)) * 5 + sidx) * 4096;
        writeout(xb, 5 * 4096);
    }
    if (sidx == 0) {
        block_sync_lds();          // writeout LDS reads complete before overwrite
        stage(false);
        block_sync_lds();
        int t0 = chunk * 4;
        unsigned short* sb = Sf + (size_t)(b * NTILE64 + t0) * 4096;
        writeout(sb, 4096);
    }
}

// ---------------- gemm_main: fragment tiles are wave-load-native -> pure
// linear global reads, NO LDS staging, NO mid-loop barriers. 4 waves:
// w<2: delta rowtile w (D_s . X_s);  w>=2: h rowtile w-2 (MSp.S + sum MT.X).
__global__ __launch_bounds__(256, 3) void gemm_main(
        const unsigned short* __restrict__ Xf, const unsigned short* __restrict__ Sf,
        const unsigned short* __restrict__ AfragW, const unsigned short* __restrict__ AfragSp,
        const float* __restrict__ c1, const float* __restrict__ rw2, const float* __restrict__ rb2,
        float* __restrict__ slearn, float* __restrict__ partial) {
    __shared__ float wred[5][2];
    __shared__ float hpart[2][5][64];
    __shared__ float w2s[320];
    __shared__ float c1s[64];
    __shared__ float rb2s[8];

    const int tid = threadIdx.x, lane = tid & 63, w = tid >> 6;
    const int hi = lane >> 5, pxm = lane & 31;
    const int bid = blockIdx.x;
    const int b = bid / NTILE64, t = bid % NTILE64;
    const int pix0 = t * 64;

    for (int i = tid; i < 320; i += 256) w2s[i] = rw2[i];
    if (tid < 64) c1s[tid] = c1[tid];
    if (tid < 5)  rb2s[tid] = rb2[tid];

    const bf16x8* xt = (const bf16x8*)(Xf + ((size_t)(b * NTILE64 + t) * 5) * 4096);
    const bf16x8* st = (const bf16x8*)(Sf + (size_t)(b * NTILE64 + t) * 4096);
    const bf16x8* afw = (const bf16x8*)AfragW + lane;

    if (w < 2) {
        bf16x8 bXc[8], bXn[8], fDc[4], fDn[4];
        #pragma unroll
        for (int i = 0; i < 8; ++i) bXc[i] = xt[i * 64 + lane];            // X0
        #pragma unroll
        for (int kt = 0; kt < 4; ++kt) fDc[kt] = afw[((0 * 4 + w) * 4 + kt) * 64];
        #pragma unroll
        for (int s = 0; s < 5; ++s) {
            if (s < 4) {
                #pragma unroll
                for (int i = 0; i < 8; ++i) bXn[i] = xt[(size_t)(s + 1) * 512 + i * 64 + lane];
                #pragma unroll
                for (int kt = 0; kt < 4; ++kt) fDn[kt] = afw[(((s + 1) * 4 + w) * 4 + kt) * 64];
            }
            f32x16 d0, d1;
            #pragma unroll
            for (int i = 0; i < 16; ++i) { d0[i] = 0.f; d1[i] = 0.f; }
            #pragma unroll
            for (int kt = 0; kt < 4; ++kt) {
                d0 = __builtin_amdgcn_mfma_f32_32x32x16_bf16(fDc[kt], bXc[kt],     d0, 0, 0, 0);
                d1 = __builtin_amdgcn_mfma_f32_32x32x16_bf16(fDc[kt], bXc[4 + kt], d1, 0, 0, 0);
            }
            float sq = 0.f;
            #pragma unroll
            for (int i = 0; i < 16; ++i) { sq = fmaf(d0[i], d0[i], sq); sq = fmaf(d1[i], d1[i], sq); }
            #pragma unroll
            for (int m = 1; m < 64; m <<= 1) sq += __shfl_xor(sq, m, 64);
            if (lane == 0) wred[s][w] = sq;
            if (s < 4) {
                #pragma unroll
                for (int i = 0; i < 8; ++i) bXc[i] = bXn[i];
                #pragma unroll
                for (int kt = 0; kt < 4; ++kt) fDc[kt] = fDn[kt];
            }
        }
    } else {
        const int r = w - 2;
        f32x16 h0, h1;
        #pragma unroll
        for (int i = 0; i < 16; ++i) { h0[i] = 0.f; h1[i] = 0.f; }
        {
            bf16x8 bS[8], msf[4];
            #pragma unroll
            for (int i = 0; i < 8; ++i) bS[i] = st[i * 64 + lane];
            const bf16x8* asp = (const bf16x8*)AfragSp + lane;
            #pragma unroll
            for (int kt = 0; kt < 4; ++kt) msf[kt] = asp[(r * 4 + kt) * 64];
            #pragma unroll
            for (int kt = 0; kt < 4; ++kt) {
                h0 = __builtin_amdgcn_mfma_f32_32x32x16_bf16(msf[kt], bS[kt],     h0, 0, 0, 0);
                h1 = __builtin_amdgcn_mfma_f32_32x32x16_bf16(msf[kt], bS[4 + kt], h1, 0, 0, 0);
            }
        }
        bf16x8 bXc[8], bXn[8], fMc[4], fMn[4];
        #pragma unroll
        for (int i = 0; i < 8; ++i) bXc[i] = xt[i * 64 + lane];
        #pragma unroll
        for (int kt = 0; kt < 4; ++kt) fMc[kt] = afw[((0 * 4 + 2 + r) * 4 + kt) * 64];
        #pragma unroll
        for (int s = 0; s < 5; ++s) {
            if (s < 4) {
                #pragma unroll
                for (int i = 0; i < 8; ++i) bXn[i] = xt[(size_t)(s + 1) * 512 + i * 64 + lane];
                #pragma unroll
                for (int kt = 0; kt < 4; ++kt) fMn[kt] = afw[(((s + 1) * 4 + 2 + r) * 4 + kt) * 64];
            }
            #pragma unroll
            for (int kt = 0; kt < 4; ++kt) {
                h0 = __builtin_amdgcn_mfma_f32_32x32x16_bf16(fMc[kt], bXc[kt],     h0, 0, 0, 0);
                h1 = __builtin_amdgcn_mfma_f32_32x32x16_bf16(fMc[kt], bXc[4 + kt], h1, 0, 0, 0);
            }
            if (s < 4) {
                #pragma unroll
                for (int i = 0; i < 8; ++i) bXc[i] = bXn[i];
                #pragma unroll
                for (int kt = 0; kt < 4; ++kt) fMc[kt] = fMn[kt];
            }
        }
        // relu(h+c1), w2 dot
        #pragma unroll
        for (int i = 0; i < 16; ++i) {
            int row = (i & 3) + 8 * (i >> 2) + 4 * hi + 32 * r;
            h0[i] = fmaxf(h0[i] + c1s[row], 0.f);
            h1[i] = fmaxf(h1[i] + c1s[row], 0.f);
        }
        #pragma unroll
        for (int sp = 0; sp < 5; ++sp) {
            float d0 = 0.f, d1 = 0.f;
            #pragma unroll
            for (int i = 0; i < 16; ++i) {
                int row = (i & 3) + 8 * (i >> 2) + 4 * hi + 32 * r;
                d0 = fmaf(w2s[sp * 64 + row], h0[i], d0);
                d1 = fmaf(w2s[sp * 64 + row], h1[i], d1);
            }
            d0 += __shfl_xor(d0, 32, 64);
            d1 += __shfl_xor(d1, 32, 64);
            if (hi == 0) { hpart[r][sp][pxm] = d0; hpart[r][sp][32 + pxm] = d1; }
        }
    }
    block_sync_lds();
    if (tid < 5) partial[bid * 5 + tid] = wred[tid][0] + wred[tid][1];
    for (int i = tid; i < 320; i += 256) {
        int sp = i >> 6, px = i & 63;
        slearn[((size_t)(b * 5 + sp)) * HWSZ + pix0 + px] =
            hpart[0][sp][px] + hpart[1][sp][px] + rb2s[sp];
    }
}

// ---------------- fallback (r7 structure, best verified single-pass: 56.6 us)
__global__ __launch_bounds__(256, 4) void fused_fallback(
        const float* __restrict__ S, const float* __restrict__ T,
        const unsigned short* __restrict__ AfragW, const unsigned short* __restrict__ AfragMS2,
        const float* __restrict__ c1, const float* __restrict__ rw2, const float* __restrict__ rb2,
        float* __restrict__ slearn, float* __restrict__ partial) {
    __shared__ __align__(16) unsigned short sTile[4096];
    __shared__ __align__(16) unsigned short tbuf[2][4096];
    __shared__ float hpart[2][5][64];
    __shared__ float wred[5][2];
    __shared__ float w2s[320];
    __shared__ float c1s[64];
    __shared__ float rb2s[8];

    const int tid = threadIdx.x, lane = tid & 63, w = tid >> 6;
    const int hi = lane >> 5, pxm = lane & 31;
    const int blk = blockIdx.x;
    const int b = blk / 576;
    const int pix0 = (blk % 576) * 64;
    const int o8 = tid >> 5, q = tid & 31;
    const int skt = o8 >> 1, shh = o8 & 1;
    const float* Sp = S + ((size_t)(b * 64 + 8 * o8)) * HWSZ + pix0 + 2 * q;
    const float* Tp = T + ((size_t)(b * 5 * 64 + 8 * o8)) * HWSZ + pix0 + 2 * q;

    float2 R[8];
    #pragma unroll
    for (int j = 0; j < 8; ++j) R[j] = *(const float2*)(Sp + (size_t)j * HWSZ);
    for (int i = tid; i < 320; i += 256) w2s[i] = rw2[i];
    if (tid < 64) c1s[tid] = c1[tid];
    if (tid < 5)  rb2s[tid] = rb2[tid];

    auto packWrite = [&](unsigned short* dst) {
        #pragma unroll
        for (int h2 = 0; h2 < 2; ++h2) {
            int px = 2 * q + h2;
            int ct = px >> 5, slot = (px & 31) ^ ct;
            u32x4 v;
            #pragma unroll
            for (int jj = 0; jj < 4; ++jj) {
                float a = h2 ? R[2 * jj].y : R[2 * jj].x;
                float c = h2 ? R[2 * jj + 1].y : R[2 * jj + 1].x;
                v[jj] = (unsigned)f2bf(a) | ((unsigned)f2bf(c) << 16);
            }
            *(u32x4*)&dst[(((ct * 4 + skt) * 64) + shh * 32 + slot) * 8] = v;
        }
    };
    packWrite(sTile);
    #pragma unroll
    for (int j = 0; j < 8; ++j) R[j] = *(const float2*)(Tp + (size_t)j * HWSZ);

    const bf16x8* afw = (const bf16x8*)AfragW + lane;
    bf16x8 fr0[4], fr1[4];
    #pragma unroll
    for (int kt = 0; kt < 4; ++kt) fr0[kt] = afw[((0 * 4 + w) * 4 + kt) * 64];
    bf16x8 ms2f[4];
    if (w >= 2) {
        const bf16x8* am = (const bf16x8*)AfragMS2 + lane;
        #pragma unroll
        for (int kt = 0; kt < 4; ++kt) ms2f[kt] = am[((w - 2) * 4 + kt) * 64];
    }
    block_sync_lds();

    auto ldsB = [&](const unsigned short* buf, int ct, int kt) -> bf16x8 {
        return *(const bf16x8*)&buf[(((ct * 4 + kt) * 64) + hi * 32 + (pxm ^ ct)) * 8];
    };

    f32x16 acc0, acc1;
    #pragma unroll
    for (int i = 0; i < 16; ++i) { acc0[i] = 0.f; acc1[i] = 0.f; }
    if (w >= 2) {
        #pragma unroll
        for (int kt = 0; kt < 4; ++kt) {
            acc0 = __builtin_amdgcn_mfma_f32_32x32x16_bf16(ms2f[kt], ldsB(sTile, 0, kt), acc0, 0, 0, 0);
            acc1 = __builtin_amdgcn_mfma_f32_32x32x16_bf16(ms2f[kt], ldsB(sTile, 1, kt), acc1, 0, 0, 0);
        }
    }
    packWrite(tbuf[0]);
    #pragma unroll
    for (int j = 0; j < 8; ++j) R[j] = *(const float2*)(Tp + (size_t)(64 + j) * HWSZ);
    block_sync_lds();

    #pragma unroll
    for (int s = 0; s < 5; ++s) {
        const unsigned short* cur = tbuf[s & 1];
        unsigned short* nxt = tbuf[(s + 1) & 1];
        bf16x8* fcur = (s & 1) ? fr1 : fr0;
        bf16x8* fnxt = (s & 1) ? fr0 : fr1;
        if (s < 4) {
            #pragma unroll
            for (int kt = 0; kt < 4; ++kt) fnxt[kt] = afw[(((s + 1) * 4 + w) * 4 + kt) * 64];
        }
        if (w < 2) {
            #pragma unroll
            for (int i = 0; i < 16; ++i) { acc0[i] = 0.f; acc1[i] = 0.f; }
            #pragma unroll
            for (int kt = 0; kt < 4; ++kt) {
                acc0 = __builtin_amdgcn_mfma_f32_32x32x16_bf16(fcur[kt], ldsB(sTile, 0, kt), acc0, 0, 0, 0);
                acc1 = __builtin_amdgcn_mfma_f32_32x32x16_bf16(fcur[kt], ldsB(sTile, 1, kt), acc1, 0, 0, 0);
            }
            #pragma unroll
            for (int i = 0; i < 16; ++i) { acc0[i] = -acc0[i]; acc1[i] = -acc1[i]; }
            #pragma unroll
            for (int kt = 0; kt < 4; ++kt) {
                acc0 = __builtin_amdgcn_mfma_f32_32x32x16_bf16(fcur[kt], ldsB(cur, 0, kt), acc0, 0, 0, 0);
                acc1 = __builtin_amdgcn_mfma_f32_32x32x16_bf16(fcur[kt], ldsB(cur, 1, kt), acc1, 0, 0, 0);
            }
            float sq = 0.f;
            #pragma unroll
            for (int i = 0; i < 16; ++i) { sq = fmaf(acc0[i], acc0[i], sq); sq = fmaf(acc1[i], acc1[i], sq); }
            #pragma unroll
            for (int m = 1; m < 64; m <<= 1) sq += __shfl_xor(sq, m, 64);
            if (lane == 0) wred[s][w] = sq;
        } else {
            #pragma unroll
            for (int kt = 0; kt < 4; ++kt) {
                acc0 = __builtin_amdgcn_mfma_f32_32x32x16_bf16(fcur[kt], ldsB(cur, 0, kt), acc0, 0, 0, 0);
                acc1 = __builtin_amdgcn_mfma_f32_32x32x16_bf16(fcur[kt], ldsB(cur, 1, kt), acc1, 0, 0, 0);
            }
        }
        if (s < 4) {
            packWrite(nxt);
            if (s < 3) {
                #pragma unroll
                for (int j = 0; j < 8; ++j)
                    R[j] = *(const float2*)(Tp + (size_t)((s + 2) * 64 + j) * HWSZ);
            }
        }
        block_sync_lds();
    }

    if (w >= 2) {
        #pragma unroll
        for (int i = 0; i < 16; ++i) {
            int row = (i & 3) + 8 * (i >> 2) + 4 * hi + 32 * (w - 2);
            acc0[i] = fmaxf(acc0[i] + c1s[row], 0.f);
            acc1[i] = fmaxf(acc1[i] + c1s[row], 0.f);
        }
        #pragma unroll
        for (int sp = 0; sp < 5; ++sp) {
            float d0 = 0.f, d1 = 0.f;
            #pragma unroll
            for (int i = 0; i < 16; ++i) {
                int row = (i & 3) + 8 * (i >> 2) + 4 * hi + 32 * (w - 2);
                d0 = fmaf(w2s[sp * 64 + row], acc0[i], d0);
                d1 = fmaf(w2s[sp * 64 + row], acc1[i], d1);
            }
            d0 += __shfl_xor(d0, 32, 64);
            d1 += __shfl_xor(d1, 32, 64);
            if (hi == 0) { hpart[w - 2][sp][pxm] = d0; hpart[w - 2][sp][32 + pxm] = d1; }
        }
    }
    block_sync_lds();
    if (tid < 5) partial[blk * 5 + tid] = wred[tid][0] + wred[tid][1];
    for (int i = tid; i < 320; i += 256) {
        int sp = i >> 6, px = i & 63;
        slearn[((size_t)(b * 5 + sp)) * HWSZ + pix0 + px] =
            hpart[0][sp][px] + hpart[1][sp][px] + rb2s[sp];
    }
}

// ---------------- reduce proxy partials -> per-s score (deterministic)
__global__ void score_kernel(const float* __restrict__ partial,
                             const float* __restrict__ ema_proxy,
                             float* __restrict__ scoreBuf) {
    __shared__ float red[256];
    __shared__ float cur[5];
    int tid = threadIdx.x;
    for (int s = 0; s < 5; ++s) {
        float sum = 0.f;
        for (int i = tid; i < NBLK; i += 256) sum += partial[i * 5 + s];
        red[tid] = sum;
        __syncthreads();
        for (int off = 128; off > 0; off >>= 1) {
            if (tid < off) red[tid] += red[tid + off];
            __syncthreads();
        }
        if (tid == 0) cur[s] = red[0] * (1.0f / (64.0f * 2.0f * HWSZ));
        __syncthreads();
    }
    if (tid == 0) {
        float impr[5]; float m = 0.f;
        for (int s = 0; s < 5; ++s) { impr[s] = ema_proxy[s] - cur[s]; m += impr[s]; }
        m *= 0.2f;
        for (int s = 0; s < 5; ++s) {
            float adv = impr[s] - m;
            float c = cur[s];
            float below = fmaxf(0.05f - c, 0.f);
            float above = fmaxf(c - 0.2f, 0.f);
            float band = -(below * below + above * above);
            scoreBuf[s] = 1.0f * adv + 0.5f * band;
        }
    }
}

// ---------------- per-pixel softmax over Sn=5
__global__ void softmax_kernel(const float* __restrict__ slearn,
                               const float* __restrict__ scoreBuf,
                               float* __restrict__ out) {
    int i = blockIdx.x * 256 + threadIdx.x;
    if (i >= 2 * HWSZ) return;
    int b = i / HWSZ, p = i % HWSZ;
    float l[5];
    float mx = -1e30f;
    #pragma unroll
    for (int s = 0; s < 5; ++s) {
        float v = (0.5f * scoreBuf[s] + 0.5f * slearn[((size_t)(b * 5 + s)) * HWSZ + p]) / 0.7f;
        l[s] = v;
        mx = fmaxf(mx, v);
    }
    float sum = 0.f;
    #pragma unroll
    for (int s = 0; s < 5; ++s) { l[s] = expf(l[s] - mx); sum += l[s]; }
    float inv = 1.0f / sum;
    #pragma unroll
    for (int s = 0; s < 5; ++s) out[((size_t)(b * 5 + s)) * HWSZ + p] = l[s] * inv;
}

extern "C" void kernel_launch(void* const* d_in, const int* in_sizes, int n_in,
                              void* d_out, int out_size, void* d_ws, size_t ws_size,
                              hipStream_t stream) {
    const float* S   = (const float*)d_in[0];
    const float* T   = (const float*)d_in[1];
    const float* aw  = (const float*)d_in[2];
    const float* ab  = (const float*)d_in[3];
    const float* rw1 = (const float*)d_in[4];
    const float* rb1 = (const float*)d_in[5];
    const float* rw2 = (const float*)d_in[6];
    const float* rb2 = (const float*)d_in[7];
    const float* mu  = (const float*)d_in[8];
    const float* sg  = (const float*)d_in[9];
    const float* ep  = (const float*)d_in[10];

    float* ws = (float*)d_ws;
    float* c1f      = ws;                                        // 64
    float* scoreBuf = ws + 64;                                   // 8
    float* partial  = ws + 72;                                   // 5760
    unsigned short* AfragW   = (unsigned short*)(ws + 5832);     // 40960 u16
    unsigned short* AfragSp  = (unsigned short*)(ws + 26312);    // 4096 u16
    unsigned short* AfragMS2 = (unsigned short*)(ws + 28360);    // 4096 u16
    float* slearn   = ws + 30408;                                // 368640
    unsigned short* Xf = (unsigned short*)(ws + 399048);         // 23,592,960 u16
    unsigned short* Sf = (unsigned short*)(ws + 12195528);       // 4,718,592 u16
    const size_t NEED_BYTES = 14554824UL * 4UL;                  // ~58.2 MB
    float* out = (float*)d_out;

    pre_all<<<193, 256, 0, stream>>>(rw1, rb1, aw, ab, mu, sg, AfragW, AfragMS2, AfragSp, c1f);
    if (ws_size >= NEED_BYTES) {
        xpose<<<1440, 256, 0, stream>>>(S, T, Xf, Sf);
        gemm_main<<<NBLK, 256, 0, stream>>>(Xf, Sf, AfragW, AfragSp, c1f, rw2, rb2, slearn, partial);
    } else {
        fused_fallback<<<NBLK, 256, 0, stream>>>(S, T, AfragW, AfragMS2, c1f, rw2, rb2, slearn, partial);
    }
    score_kernel<<<1, 256, 0, stream>>>(partial, ep, scoreBuf);
    softmax_kernel<<<288, 256, 0, stream>>>(slearn, scoreBuf, out);
}

// Round 13
// 55.649 us; speedup vs baseline: 1.6133x; 1.6133x over previous
//
#include <hip/hip_runtime.h>
#include <math.h>

#define HWSZ 36864            // 192*192
#define NBLK4 1152            // 2 images * 576 tiles of 64 px

typedef short bf16x8 __attribute__((ext_vector_type(8)));
typedef float f32x16 __attribute__((ext_vector_type(16)));
typedef unsigned int u32x4 __attribute__((ext_vector_type(4)));

__device__ __forceinline__ unsigned short f2bf(float x) {
    unsigned u = __float_as_uint(x);
    return (unsigned short)((u + 0x7fffu + ((u >> 16) & 1u)) >> 16);  // RNE
}

// barrier that does NOT drain vmcnt: in-flight global loads survive (T4)
__device__ __forceinline__ void block_sync_lds() {
    __builtin_amdgcn_sched_barrier(0);
    asm volatile("s_waitcnt lgkmcnt(0)" ::: "memory");
    __builtin_amdgcn_s_barrier();
    __builtin_amdgcn_sched_barrier(0);
}

// ---------------- single precompute kernel: weights folded straight into
// MFMA A-fragments (bf16). AfragW [s][r(4)][kt(4)][lane(64)][e(8)]:
//   r<2: D_s rows (delta), r>=2: MT_s rows (h).  AfragMS2 [r(2)][kt][lane][e]:
//   MS2 = MSp - sum_s MT_s  (h = c1 + MS2*S + sum_s MT_s*T_s).
__global__ void pre_all(const float* __restrict__ rw1, const float* __restrict__ rb1,
                        const float* __restrict__ aw, const float* __restrict__ ab,
                        const float* __restrict__ mu, const float* __restrict__ sg,
                        unsigned short* __restrict__ AfragW,
                        unsigned short* __restrict__ AfragMS2, float* __restrict__ c1) {
    int i = blockIdx.x * 256 + threadIdx.x;
    if (i < 40960) {
        int s = i / 8192, rem = i % 8192;
        int r = rem / 2048, rem2 = rem % 2048;
        int t = rem2 / 512, q = rem2 % 512;
        int l = q >> 3, e = q & 7;
        int R = 32 * r + (l & 31);
        int k = 16 * t + 8 * (l >> 5) + e;
        float v;
        if (R < 64) {
            v = aw[s * 4096 + R * 64 + k] / sg[s * 64 + R];        // D_s[R][k]
        } else {
            int o = R - 64;                                        // MT_s[o][k]
            const float* wp = rw1 + o * 960 + s * 192;
            const float* A  = aw + s * 4096 + k;
            const float* G  = sg + s * 64;
            float sum = 0.f;
            #pragma unroll 8
            for (int d = 0; d < 64; ++d)
                sum = fmaf(wp[64 + d] + wp[128 + d], A[d * 64] / G[d], sum);
            v = sum;
        }
        AfragW[i] = f2bf(v);
    } else if (i < 45056) {
        int j = i - 40960;
        int r = j / 2048, rem2 = j % 2048;
        int t = rem2 / 512, q = rem2 % 512;
        int l = q >> 3, e = q & 7;
        int o = 32 * r + (l & 31);
        int k = 16 * t + 8 * (l >> 5) + e;
        // MS2[o][k] = sum_s sum_d (w1[o,s*192+d] - w1[o,s*192+128+d]) * D_s[d][k]
        float sum = 0.f;
        for (int s = 0; s < 5; ++s) {
            const float* wp = rw1 + o * 960 + s * 192;
            const float* A  = aw + s * 4096 + k;
            const float* G  = sg + s * 64;
            #pragma unroll 8
            for (int d = 0; d < 64; ++d)
                sum = fmaf(wp[d] - wp[128 + d], A[d * 64] / G[d], sum);
        }
        AfragMS2[j] = f2bf(sum);
    } else if (i < 45120) {
        int o = i - 45056;
        float sum = rb1[o];
        for (int s = 0; s < 5; ++s) {
            const float* wp = rw1 + o * 960 + s * 192;
            #pragma unroll 8
            for (int d = 0; d < 64; ++d) {
                int sd = s * 64 + d;
                sum = fmaf(wp[d] + wp[64 + d], (ab[sd] - mu[sd]) / sg[sd], sum);
            }
        }
        c1[o] = sum;
    }
}

// ---------------- fused main (r7 structure, best measured: 56.6 us total):
// 4 waves / 64 px; S staged once; T pure stream; delta = D*T - D*S;
// lgkmcnt-only barriers; 1-deep T prefetch.
__global__ __launch_bounds__(256, 4) void fused_main(
        const float* __restrict__ S, const float* __restrict__ T,
        const unsigned short* __restrict__ AfragW, const unsigned short* __restrict__ AfragMS2,
        const float* __restrict__ c1, const float* __restrict__ rw2, const float* __restrict__ rb2,
        float* __restrict__ slearn, float* __restrict__ partial) {
    __shared__ __align__(16) unsigned short sTile[4096];   // S bf16, frag order, 8KB
    __shared__ __align__(16) unsigned short tbuf[2][4096]; // T dbuf, 16KB
    __shared__ float hpart[2][5][64];
    __shared__ float wred[5][2];
    __shared__ float w2s[320];
    __shared__ float c1s[64];
    __shared__ float rb2s[8];

    const int tid = threadIdx.x, lane = tid & 63, w = tid >> 6;
    const int hi = lane >> 5, pxm = lane & 31;
    const int blk = blockIdx.x;
    const int b = blk / 576;
    const int pix0 = (blk % 576) * 64;

    // staging: thread = (ch octet o8, px pair 2q..2q+1)
    const int o8 = tid >> 5, q = tid & 31;
    const int skt = o8 >> 1, shh = o8 & 1;
    const float* Sp = S + ((size_t)(b * 64 + 8 * o8)) * HWSZ + pix0 + 2 * q;
    const float* Tp = T + ((size_t)(b * 5 * 64 + 8 * o8)) * HWSZ + pix0 + 2 * q;

    float2 R[8];
    #pragma unroll
    for (int j = 0; j < 8; ++j) R[j] = *(const float2*)(Sp + (size_t)j * HWSZ);

    for (int i = tid; i < 320; i += 256) w2s[i] = rw2[i];
    if (tid < 64) c1s[tid] = c1[tid];
    if (tid < 5)  rb2s[tid] = rb2[tid];

    // pack R (8 ch x 2 px) -> fragment-order tile; slot XOR-swizzled by coltile
    auto packWrite = [&](unsigned short* dst) {
        #pragma unroll
        for (int h2 = 0; h2 < 2; ++h2) {
            int px = 2 * q + h2;
            int ct = px >> 5, slot = (px & 31) ^ ct;
            u32x4 v;
            #pragma unroll
            for (int jj = 0; jj < 4; ++jj) {
                float a = h2 ? R[2 * jj].y : R[2 * jj].x;
                float c = h2 ? R[2 * jj + 1].y : R[2 * jj + 1].x;
                v[jj] = (unsigned)f2bf(a) | ((unsigned)f2bf(c) << 16);
            }
            *(u32x4*)&dst[(((ct * 4 + skt) * 64) + shh * 32 + slot) * 8] = v;
        }
    };

    packWrite(sTile);

    // T0 loads in flight under prologue
    #pragma unroll
    for (int j = 0; j < 8; ++j) R[j] = *(const float2*)(Tp + (size_t)j * HWSZ);

    // fragment window prefetch (s=0) + MS2 frags
    const bf16x8* afw = (const bf16x8*)AfragW + lane;
    bf16x8 fr0[4], fr1[4];
    #pragma unroll
    for (int kt = 0; kt < 4; ++kt) fr0[kt] = afw[((0 * 4 + w) * 4 + kt) * 64];
    bf16x8 ms2f[4];
    if (w >= 2) {
        const bf16x8* am = (const bf16x8*)AfragMS2 + lane;
        #pragma unroll
        for (int kt = 0; kt < 4; ++kt) ms2f[kt] = am[((w - 2) * 4 + kt) * 64];
    }

    block_sync_lds();     // sTile visible

    auto ldsB = [&](const unsigned short* buf, int ct, int kt) -> bf16x8 {
        return *(const bf16x8*)&buf[(((ct * 4 + kt) * 64) + hi * 32 + (pxm ^ ct)) * 8];
    };

    f32x16 acc0, acc1;
    #pragma unroll
    for (int i = 0; i < 16; ++i) { acc0[i] = 0.f; acc1[i] = 0.f; }

    // h init: MS2 @ S (waves 2,3) — barrier-independent MFMA
    if (w >= 2) {
        #pragma unroll
        for (int kt = 0; kt < 4; ++kt) {
            acc0 = __builtin_amdgcn_mfma_f32_32x32x16_bf16(ms2f[kt], ldsB(sTile, 0, kt), acc0, 0, 0, 0);
            acc1 = __builtin_amdgcn_mfma_f32_32x32x16_bf16(ms2f[kt], ldsB(sTile, 1, kt), acc1, 0, 0, 0);
        }
    }

    packWrite(tbuf[0]);   // stage T0 (counted vmcnt wait on R only)
    #pragma unroll
    for (int j = 0; j < 8; ++j) R[j] = *(const float2*)(Tp + (size_t)(64 + j) * HWSZ);  // T1

    block_sync_lds();

    #pragma unroll
    for (int s = 0; s < 5; ++s) {
        const unsigned short* cur = tbuf[s & 1];
        unsigned short* nxt = tbuf[(s + 1) & 1];
        bf16x8* fcur = (s & 1) ? fr1 : fr0;
        bf16x8* fnxt = (s & 1) ? fr0 : fr1;
        if (s < 4) {
            #pragma unroll
            for (int kt = 0; kt < 4; ++kt) fnxt[kt] = afw[(((s + 1) * 4 + w) * 4 + kt) * 64];
        }
        if (w < 2) {
            // delta = D_s*T_s - D_s*S : seed acc with -(D_s*S)
            #pragma unroll
            for (int i = 0; i < 16; ++i) { acc0[i] = 0.f; acc1[i] = 0.f; }
            #pragma unroll
            for (int kt = 0; kt < 4; ++kt) {
                acc0 = __builtin_amdgcn_mfma_f32_32x32x16_bf16(fcur[kt], ldsB(sTile, 0, kt), acc0, 0, 0, 0);
                acc1 = __builtin_amdgcn_mfma_f32_32x32x16_bf16(fcur[kt], ldsB(sTile, 1, kt), acc1, 0, 0, 0);
            }
            #pragma unroll
            for (int i = 0; i < 16; ++i) { acc0[i] = -acc0[i]; acc1[i] = -acc1[i]; }
            #pragma unroll
            for (int kt = 0; kt < 4; ++kt) {
                acc0 = __builtin_amdgcn_mfma_f32_32x32x16_bf16(fcur[kt], ldsB(cur, 0, kt), acc0, 0, 0, 0);
                acc1 = __builtin_amdgcn_mfma_f32_32x32x16_bf16(fcur[kt], ldsB(cur, 1, kt), acc1, 0, 0, 0);
            }
            float sq = 0.f;
            #pragma unroll
            for (int i = 0; i < 16; ++i) { sq = fmaf(acc0[i], acc0[i], sq); sq = fmaf(acc1[i], acc1[i], sq); }
            #pragma unroll
            for (int m = 1; m < 64; m <<= 1) sq += __shfl_xor(sq, m, 64);
            if (lane == 0) wred[s][w] = sq;
        } else {
            #pragma unroll
            for (int kt = 0; kt < 4; ++kt) {
                acc0 = __builtin_amdgcn_mfma_f32_32x32x16_bf16(fcur[kt], ldsB(cur, 0, kt), acc0, 0, 0, 0);
                acc1 = __builtin_amdgcn_mfma_f32_32x32x16_bf16(fcur[kt], ldsB(cur, 1, kt), acc1, 0, 0, 0);
            }
        }
        if (s < 4) {
            packWrite(nxt);        // T_{s+1}
            if (s < 3) {
                #pragma unroll
                for (int j = 0; j < 8; ++j)
                    R[j] = *(const float2*)(Tp + (size_t)((s + 2) * 64 + j) * HWSZ);
            }
        }
        block_sync_lds();
    }

    // ---- epilogue: relu(h+c1), w2 dot, cross-wave row-sum via LDS ----
    if (w >= 2) {
        #pragma unroll
        for (int i = 0; i < 16; ++i) {
            int row = (i & 3) + 8 * (i >> 2) + 4 * hi + 32 * (w - 2);
            acc0[i] = fmaxf(acc0[i] + c1s[row], 0.f);
            acc1[i] = fmaxf(acc1[i] + c1s[row], 0.f);
        }
        #pragma unroll
        for (int sp = 0; sp < 5; ++sp) {
            float d0 = 0.f, d1 = 0.f;
            #pragma unroll
            for (int i = 0; i < 16; ++i) {
                int row = (i & 3) + 8 * (i >> 2) + 4 * hi + 32 * (w - 2);
                d0 = fmaf(w2s[sp * 64 + row], acc0[i], d0);
                d1 = fmaf(w2s[sp * 64 + row], acc1[i], d1);
            }
            d0 += __shfl_xor(d0, 32, 64);
            d1 += __shfl_xor(d1, 32, 64);
            if (hi == 0) { hpart[w - 2][sp][pxm] = d0; hpart[w - 2][sp][32 + pxm] = d1; }
        }
    }
    block_sync_lds();
    if (tid < 5) partial[blk * 5 + tid] = wred[tid][0] + wred[tid][1];
    for (int i = tid; i < 320; i += 256) {
        int sp = i >> 6, px = i & 63;
        slearn[((size_t)(b * 5 + sp)) * HWSZ + pix0 + px] =
            hpart[0][sp][px] + hpart[1][sp][px] + rb2s[sp];
    }
}

// ---------------- reduce proxy partials -> per-s score (deterministic)
__global__ void score_kernel(const float* __restrict__ partial,
                             const float* __restrict__ ema_proxy,
                             float* __restrict__ scoreBuf) {
    __shared__ float red[256];
    __shared__ float cur[5];
    int tid = threadIdx.x;
    for (int s = 0; s < 5; ++s) {
        float sum = 0.f;
        for (int i = tid; i < NBLK4; i += 256) sum += partial[i * 5 + s];
        red[tid] = sum;
        __syncthreads();
        for (int off = 128; off > 0; off >>= 1) {
            if (tid < off) red[tid] += red[tid + off];
            __syncthreads();
        }
        if (tid == 0) cur[s] = red[0] * (1.0f / (64.0f * 2.0f * HWSZ));
        __syncthreads();
    }
    if (tid == 0) {
        float impr[5]; float m = 0.f;
        for (int s = 0; s < 5; ++s) { impr[s] = ema_proxy[s] - cur[s]; m += impr[s]; }
        m *= 0.2f;
        for (int s = 0; s < 5; ++s) {
            float adv = impr[s] - m;
            float c = cur[s];
            float below = fmaxf(0.05f - c, 0.f);
            float above = fmaxf(c - 0.2f, 0.f);
            float band = -(below * below + above * above);
            scoreBuf[s] = 1.0f * adv + 0.5f * band;
        }
    }
}

// ---------------- per-pixel softmax over Sn=5
__global__ void softmax_kernel(const float* __restrict__ slearn,
                               const float* __restrict__ scoreBuf,
                               float* __restrict__ out) {
    int i = blockIdx.x * 256 + threadIdx.x;
    if (i >= 2 * HWSZ) return;
    int b = i / HWSZ, p = i % HWSZ;
    float l[5];
    float mx = -1e30f;
    #pragma unroll
    for (int s = 0; s < 5; ++s) {
        float v = (0.5f * scoreBuf[s] + 0.5f * slearn[((size_t)(b * 5 + s)) * HWSZ + p]) / 0.7f;
        l[s] = v;
        mx = fmaxf(mx, v);
    }
    float sum = 0.f;
    #pragma unroll
    for (int s = 0; s < 5; ++s) { l[s] = expf(l[s] - mx); sum += l[s]; }
    float inv = 1.0f / sum;
    #pragma unroll
    for (int s = 0; s < 5; ++s) out[((size_t)(b * 5 + s)) * HWSZ + p] = l[s] * inv;
}

extern "C" void kernel_launch(void* const* d_in, const int* in_sizes, int n_in,
                              void* d_out, int out_size, void* d_ws, size_t ws_size,
                              hipStream_t stream) {
    const float* S   = (const float*)d_in[0];
    const float* T   = (const float*)d_in[1];
    const float* aw  = (const float*)d_in[2];
    const float* ab  = (const float*)d_in[3];
    const float* rw1 = (const float*)d_in[4];
    const float* rb1 = (const float*)d_in[5];
    const float* rw2 = (const float*)d_in[6];
    const float* rb2 = (const float*)d_in[7];
    const float* mu  = (const float*)d_in[8];
    const float* sg  = (const float*)d_in[9];
    const float* ep  = (const float*)d_in[10];

    float* ws = (float*)d_ws;
    float* c1f      = ws;                                       // 64
    float* scoreBuf = ws + 64;                                  // 8
    float* partial  = ws + 72;                                  // 5760 (1152*5)
    unsigned short* AfragW   = (unsigned short*)(ws + 5832);    // 40960 u16 = 20480 f
    unsigned short* AfragMS2 = (unsigned short*)(ws + 26312);   // 4096 u16 = 2048 f
    float* slearn   = ws + 28360;                               // 368640
    float* out = (float*)d_out;

    pre_all<<<177, 256, 0, stream>>>(rw1, rb1, aw, ab, mu, sg, AfragW, AfragMS2, c1f);
    fused_main<<<NBLK4, 256, 0, stream>>>(S, T, AfragW, AfragMS2, c1f, rw2, rb2, slearn, partial);
    score_kernel<<<1, 256, 0, stream>>>(partial, ep, scoreBuf);
    softmax_kernel<<<288, 256, 0, stream>>>(slearn, scoreBuf, out);
}